// Round 12
// baseline (53.274 us; speedup 1.0000x reference)
//
#include <hip/hip_runtime.h>
#include <string.h>

// Fused ConvNet, single dispatch: conv7x7 s3 (3->4) -> ^2 -> FC 324->64 -> ^2 -> FC 64->10
// conv + fc1 on v_mfma_f32_16x16x32_f16; x staged as fp16 windows in LDS
// (one aligned ds_read_b128 per A-fragment).
// Round 12: R9 structure with NS=8 samples/block, grid=2048. LDS 19584 B;
// residency 6 blocks/CU vs 8 blocks/CU of work -> blocks self-stagger so the
// fc1/fc2 epilogue of early blocks overlaps the x-stream of late blocks.

typedef _Float16 f16;
typedef f16 f16x8 __attribute__((ext_vector_type(8)));
typedef __fp16 fp16x2 __attribute__((ext_vector_type(2)));
typedef float f32x4 __attribute__((ext_vector_type(4)));

#define NS     8                       // samples per block
#define YS_B   13824                   // byte offset of YS region (= WIN size)
#define LDS_B  (13824 + NS * 720)      // WIN[3][32][9][8]h + YS[NS][360]h = 19584

__device__ __forceinline__ unsigned pack_rtz(float a, float b) {
    fp16x2 h = __builtin_amdgcn_cvt_pkrtz(a, b);
    unsigned u; memcpy(&u, &h, 4); return u;
}

// stage one half-row: pack 5 float4 (10 dwords) and write 4-5 windows of 8 halves
// half 0: dwords 0..9  (cols 0..19),  windows ow = {0,1,2,3,4}
// half 1: dwords 6..15 (cols 12..31), windows ow = {5,6,7,8}
__device__ __forceinline__ void write_half(f16* wptr, const float4 ldv[5], int half) {
    unsigned h[10];
#pragma unroll
    for (int i = 0; i < 5; ++i) {
        h[2*i]   = pack_rtz(ldv[i].x, ldv[i].y);
        h[2*i+1] = pack_rtz(ldv[i].z, ldv[i].w);
    }
    const int owb = half * 4;
    if (!half) {                                  // ow 0 (direct @0)
        uint4 v; v.x = h[0]; v.y = h[1]; v.z = h[2]; v.w = h[3];
        *reinterpret_cast<uint4*>(wptr) = v;
    }
    {                                             // ow owb+1 (align @1)
        uint4 v;
        v.x = __builtin_amdgcn_alignbit(h[2], h[1], 16);
        v.y = __builtin_amdgcn_alignbit(h[3], h[2], 16);
        v.z = __builtin_amdgcn_alignbit(h[4], h[3], 16);
        v.w = __builtin_amdgcn_alignbit(h[5], h[4], 16);
        *reinterpret_cast<uint4*>(wptr + (owb + 1) * 8) = v;
    }
    {                                             // ow owb+2 (direct @3)
        uint4 v; v.x = h[3]; v.y = h[4]; v.z = h[5]; v.w = h[6];
        *reinterpret_cast<uint4*>(wptr + (owb + 2) * 8) = v;
    }
    {                                             // ow owb+3 (align @4)
        uint4 v;
        v.x = __builtin_amdgcn_alignbit(h[5], h[4], 16);
        v.y = __builtin_amdgcn_alignbit(h[6], h[5], 16);
        v.z = __builtin_amdgcn_alignbit(h[7], h[6], 16);
        v.w = __builtin_amdgcn_alignbit(h[8], h[7], 16);
        *reinterpret_cast<uint4*>(wptr + (owb + 3) * 8) = v;
    }
    {                                             // ow owb+4 (direct @6)
        uint4 v; v.x = h[6]; v.y = h[7]; v.z = h[8]; v.w = h[9];
        *reinterpret_cast<uint4*>(wptr + (owb + 4) * 8) = v;
    }
}

__global__ __launch_bounds__(256, 6) void convnet_mfma(
    const float* __restrict__ x,
    const float* __restrict__ cw,      // [4][3][7][7]
    const float* __restrict__ fc1w,    // [64][324]
    const float* __restrict__ fc1b,
    const float* __restrict__ fc2w,    // [10][64]
    const float* __restrict__ fc2b,
    float* __restrict__ out)
{
    __shared__ unsigned char lds[LDS_B];
    f16* WINH = (f16*)lds;                         // [3][32][9][8] halves (one sample)
    f16* YS   = (f16*)(lds + YS_B);                // [NS][360] halves
    float* HSQ = (float*)lds;                      // overlay on WIN (post-conv)

    const int t    = threadIdx.x;
    const int lane = t & 63;
    const int w    = t >> 6;
    const int g    = lane >> 4;
    const int lr   = lane & 15;
    const size_t base_s = (size_t)blockIdx.x * NS;

    // ---- conv W fragments (in-kernel fp16 cvt): lane holds col=lr, k=st*32+g*8..+7
    f16x8 wcf[6];
#pragma unroll
    for (int st = 0; st < 6; ++st) {
        f16x8 v = {0, 0, 0, 0, 0, 0, 0, 0};
        int seg = st * 4 + g;
        if (lr < 4 && seg <= 20) {
            int ci = seg >= 14 ? 2 : (seg >= 7 ? 1 : 0);
            int kh = seg - ci * 7;
            const float* wr = cw + ((lr * 3 + ci) * 7 + kh) * 7;
#pragma unroll
            for (int j = 0; j < 7; ++j) v[j] = (f16)wr[j];
        }
        wcf[st] = v;
    }

    // seg byte offsets (seg = st*4+g, clamped; pad segs have zero weights)
    int seg2off[6];
#pragma unroll
    for (int st = 0; st < 6; ++st) {
        int seg  = st * 4 + g;
        int segc = seg > 20 ? 20 : seg;
        int ci   = segc >= 14 ? 2 : (segc >= 7 ? 1 : 0);
        int kh   = segc - ci * 7;
        seg2off[st] = ci * 4608 + kh * 144;        // bytes: ci*(32*9*16) + kh*(9*16)
    }

    // conv tiles (6 tiles of 16 rows over 81 positions): u=3-w
    // u0(w3): {0,4}  u1(w2): {1,5}  u2(w1): {2}  u3(w0): {3}
    const int u = 3 - w;
    const int ntiles = (u < 2) ? 2 : 1;
    int rowbase[2], pbase[2];
#pragma unroll
    for (int ti = 0; ti < 2; ++ti) {
        int tile = u + ti * 4;
        int tc   = tile > 5 ? 5 : tile;
        int grow = tc * 16 + lr;
        int p    = grow > 80 ? 80 : grow;
        int oh   = (p * 57) >> 9;
        int ow   = p - oh * 9;
        rowbase[ti] = oh * 432 + ow * 16;          // bytes
        pbase[ti]   = tc * 16 + g * 4;             // C rows p = pbase + r
    }

    // staging identity: 192 threads = (ci,row) x half
    const bool stg  = t < 192;
    const int  r_   = t >> 1;                      // 0..95
    const int  half = t & 1;
    const int  sci  = r_ >> 5;
    const int  srow = r_ & 31;
    const int  goff = sci * 1024 + srow * 32 + (half ? 12 : 0);
    f16* wptr = WINH + sci * 2304 + srow * 72;

    // prologue: load + stage sample 0; zero YS tails (halves [324,360) per sample)
    float4 ldv[5];
    if (stg) {
        const float* gp = x + base_s * 3072 + goff;
#pragma unroll
        for (int i = 0; i < 5; ++i) ldv[i] = *(const float4*)(gp + 4 * i);
    }
    if (t < NS * 18) {
        int si = t / 18, d = t - si * 18;
        *(unsigned*)(YS + si * 360 + 324 + d * 2) = 0u;
    }
    if (stg) write_half(wptr, ldv, half);
    __syncthreads();

    for (int s = 0; s < NS; ++s) {
        if (s < NS - 1 && stg) {
            const float* gp = x + (base_s + s + 1) * 3072 + goff;
#pragma unroll
            for (int i = 0; i < 5; ++i) ldv[i] = *(const float4*)(gp + 4 * i);
        }
        f16* ysp = YS + s * 360;
        __builtin_amdgcn_s_setprio(1);
#pragma unroll
        for (int ti = 0; ti < 2; ++ti) {
            if (ti < ntiles) {
                const unsigned char* pA = lds + rowbase[ti];
                f32x4 acc = {0.f, 0.f, 0.f, 0.f};
#pragma unroll
                for (int st = 0; st < 6; ++st) {
                    f16x8 af = *(const f16x8*)(pA + seg2off[st]);
                    acc = __builtin_amdgcn_mfma_f32_16x16x32_f16(af, wcf[st], acc, 0, 0, 0);
                }
                if (lr < 4) {
#pragma unroll
                    for (int r = 0; r < 4; ++r) {
                        int p = pbase[ti] + r;
                        if (p < 81) {
                            float y = acc[r];
                            ysp[lr * 81 + p] = (f16)(y * y);
                        }
                    }
                }
            }
        }
        __builtin_amdgcn_s_setprio(0);
        __syncthreads();                       // WIN reads done, YS visible
        if (s < NS - 1) {
            if (stg) write_half(wptr, ldv, half);
            __syncthreads();                   // WIN ready for next sample
        }
    }

    // ---------------- fc1: M=NS samples (A-rows lr&7), N=64, K=352 ----------------
    {
        f32x4 a1 = {0.f, 0.f, 0.f, 0.f};
        const int n = w * 16 + lr;
        const float* w1r = fc1w + n * 324;
        __builtin_amdgcn_s_setprio(1);
#pragma unroll
        for (int st = 0; st < 10; ++st) {
            f16x8 av = *(const f16x8*)(YS + (lr & 7) * 360 + st * 32 + g * 8);
            float4 v0 = *(const float4*)(w1r + st * 32 + g * 8);
            float4 v1 = *(const float4*)(w1r + st * 32 + g * 8 + 4);
            float vv[8] = {v0.x, v0.y, v0.z, v0.w, v1.x, v1.y, v1.z, v1.w};
            f16x8 bh, bl;
#pragma unroll
            for (int j = 0; j < 8; ++j) {
                f16 hi = (f16)vv[j];
                bh[j] = hi;
                bl[j] = (f16)(vv[j] - (float)hi);
            }
            a1 = __builtin_amdgcn_mfma_f32_16x16x32_f16(av, bh, a1, 0, 0, 0);
            a1 = __builtin_amdgcn_mfma_f32_16x16x32_f16(av, bl, a1, 0, 0, 0);
        }
        {   // st = 10: k = 320..351, only 320..323 carry data (g==0, j<4)
            f16x8 av = *(const f16x8*)(YS + (lr & 7) * 360 + 320 + g * 8);
            f16x8 bh = {0,0,0,0,0,0,0,0}, bl = {0,0,0,0,0,0,0,0};
            if (g == 0) {
                float4 v0 = *(const float4*)(w1r + 320);
                float vv[4] = {v0.x, v0.y, v0.z, v0.w};
#pragma unroll
                for (int j = 0; j < 4; ++j) {
                    f16 hi = (f16)vv[j];
                    bh[j] = hi;
                    bl[j] = (f16)(vv[j] - (float)hi);
                }
            }
            a1 = __builtin_amdgcn_mfma_f32_16x16x32_f16(av, bh, a1, 0, 0, 0);
            a1 = __builtin_amdgcn_mfma_f32_16x16x32_f16(av, bl, a1, 0, 0, 0);
        }
        __builtin_amdgcn_s_setprio(0);
        float bias = fc1b[n];
#pragma unroll
        for (int r = 0; r < 4; ++r) {
            int s = g * 4 + r;                 // sample row; valid for s < NS
            if (s < NS) {
                float h = a1[r] + bias;
                HSQ[s * 65 + n] = h * h;       // overlays WIN (conv done)
            }
        }
    }
    __syncthreads();

    // ---------------- fc2: NS*10 outputs ----------------
    if (t < NS * 10) {
        int sj = t / 10, j = t - sj * 10;
        float a = fc2b[j];
        const float* wr = fc2w + j * 64;
        const float* hv = &HSQ[sj * 65];
#pragma unroll
        for (int i = 0; i < 64; ++i) a += wr[i] * hv[i];
        out[(base_s + sj) * 10 + j] = a;
    }
}

extern "C" void kernel_launch(void* const* d_in, const int* in_sizes, int n_in,
                              void* d_out, int out_size, void* d_ws, size_t ws_size,
                              hipStream_t stream) {
    const float* x    = (const float*)d_in[0];
    const float* cw   = (const float*)d_in[1];
    const float* fc1w = (const float*)d_in[2];
    const float* fc1b = (const float*)d_in[3];
    const float* fc2w = (const float*)d_in[4];
    const float* fc2b = (const float*)d_in[5];
    float* out = (float*)d_out;

    const int B = in_sizes[0] / 3072;      // 16384
    hipLaunchKernelGGL(convnet_mfma, dim3(B / NS), dim3(256), 0, stream,
                       x, cw, fc1w, fc1b, fc2w, fc2b, out);
}

// Round 13
// 41.494 us; speedup vs baseline: 1.2839x; 1.2839x over previous
//
#include <hip/hip_runtime.h>
#include <string.h>

// Fused ConvNet, single dispatch: conv7x7 s3 (3->4) -> ^2 -> FC 324->64 -> ^2 -> FC 64->10
// conv + fc1 on v_mfma_f32_16x16x32_f16; x staged as fp16 windows in LDS
// (one aligned ds_read_b128 per A-fragment).
// Round 13: NS=32 samples/block, grid=512 -> halve per-block fixed work again
// (NS trend: 8->53.3us, 16->45.5us). fc1 = two M-tiles sharing one hi/lo
// weight-load/split. lb(256,2) relaxes VGPR cap (2 blocks/CU by grid anyway).

typedef _Float16 f16;
typedef f16 f16x8 __attribute__((ext_vector_type(8)));
typedef __fp16 fp16x2 __attribute__((ext_vector_type(2)));
typedef float f32x4 __attribute__((ext_vector_type(4)));

#define NS     32                      // samples per block
#define YS_B   13824                   // byte offset of YS region (= WIN size)
#define LDS_B  (13824 + NS * 720)      // WIN[3][32][9][8]h + YS[NS][360]h = 36864

__device__ __forceinline__ unsigned pack_rtz(float a, float b) {
    fp16x2 h = __builtin_amdgcn_cvt_pkrtz(a, b);
    unsigned u; memcpy(&u, &h, 4); return u;
}

// stage one half-row: pack 5 float4 (10 dwords) and write 4-5 windows of 8 halves
// half 0: dwords 0..9  (cols 0..19),  windows ow = {0,1,2,3,4}
// half 1: dwords 6..15 (cols 12..31), windows ow = {5,6,7,8}
__device__ __forceinline__ void write_half(f16* wptr, const float4 ldv[5], int half) {
    unsigned h[10];
#pragma unroll
    for (int i = 0; i < 5; ++i) {
        h[2*i]   = pack_rtz(ldv[i].x, ldv[i].y);
        h[2*i+1] = pack_rtz(ldv[i].z, ldv[i].w);
    }
    const int owb = half * 4;
    if (!half) {                                  // ow 0 (direct @0)
        uint4 v; v.x = h[0]; v.y = h[1]; v.z = h[2]; v.w = h[3];
        *reinterpret_cast<uint4*>(wptr) = v;
    }
    {                                             // ow owb+1 (align @1)
        uint4 v;
        v.x = __builtin_amdgcn_alignbit(h[2], h[1], 16);
        v.y = __builtin_amdgcn_alignbit(h[3], h[2], 16);
        v.z = __builtin_amdgcn_alignbit(h[4], h[3], 16);
        v.w = __builtin_amdgcn_alignbit(h[5], h[4], 16);
        *reinterpret_cast<uint4*>(wptr + (owb + 1) * 8) = v;
    }
    {                                             // ow owb+2 (direct @3)
        uint4 v; v.x = h[3]; v.y = h[4]; v.z = h[5]; v.w = h[6];
        *reinterpret_cast<uint4*>(wptr + (owb + 2) * 8) = v;
    }
    {                                             // ow owb+3 (align @4)
        uint4 v;
        v.x = __builtin_amdgcn_alignbit(h[5], h[4], 16);
        v.y = __builtin_amdgcn_alignbit(h[6], h[5], 16);
        v.z = __builtin_amdgcn_alignbit(h[7], h[6], 16);
        v.w = __builtin_amdgcn_alignbit(h[8], h[7], 16);
        *reinterpret_cast<uint4*>(wptr + (owb + 3) * 8) = v;
    }
    {                                             // ow owb+4 (direct @6)
        uint4 v; v.x = h[6]; v.y = h[7]; v.z = h[8]; v.w = h[9];
        *reinterpret_cast<uint4*>(wptr + (owb + 4) * 8) = v;
    }
}

__global__ __launch_bounds__(256, 2) void convnet_mfma(
    const float* __restrict__ x,
    const float* __restrict__ cw,      // [4][3][7][7]
    const float* __restrict__ fc1w,    // [64][324]
    const float* __restrict__ fc1b,
    const float* __restrict__ fc2w,    // [10][64]
    const float* __restrict__ fc2b,
    float* __restrict__ out)
{
    __shared__ unsigned char lds[LDS_B];
    f16* WINH = (f16*)lds;                         // [3][32][9][8] halves (one sample)
    f16* YS   = (f16*)(lds + YS_B);                // [NS][360] halves
    float* HSQ = (float*)lds;                      // overlay on WIN (post-conv), [NS][65]

    const int t    = threadIdx.x;
    const int lane = t & 63;
    const int w    = t >> 6;
    const int g    = lane >> 4;
    const int lr   = lane & 15;
    const size_t base_s = (size_t)blockIdx.x * NS;

    // ---- conv W fragments (in-kernel fp16 cvt): lane holds col=lr, k=st*32+g*8..+7
    f16x8 wcf[6];
#pragma unroll
    for (int st = 0; st < 6; ++st) {
        f16x8 v = {0, 0, 0, 0, 0, 0, 0, 0};
        int seg = st * 4 + g;
        if (lr < 4 && seg <= 20) {
            int ci = seg >= 14 ? 2 : (seg >= 7 ? 1 : 0);
            int kh = seg - ci * 7;
            const float* wr = cw + ((lr * 3 + ci) * 7 + kh) * 7;
#pragma unroll
            for (int j = 0; j < 7; ++j) v[j] = (f16)wr[j];
        }
        wcf[st] = v;
    }

    // seg byte offsets (seg = st*4+g, clamped; pad segs have zero weights)
    int seg2off[6];
#pragma unroll
    for (int st = 0; st < 6; ++st) {
        int seg  = st * 4 + g;
        int segc = seg > 20 ? 20 : seg;
        int ci   = segc >= 14 ? 2 : (segc >= 7 ? 1 : 0);
        int kh   = segc - ci * 7;
        seg2off[st] = ci * 4608 + kh * 144;        // bytes: ci*(32*9*16) + kh*(9*16)
    }

    // conv tiles (6 tiles of 16 rows over 81 positions): u=3-w
    // u0(w3): {0,4}  u1(w2): {1,5}  u2(w1): {2}  u3(w0): {3}
    const int u = 3 - w;
    const int ntiles = (u < 2) ? 2 : 1;
    int rowbase[2], pbase[2];
#pragma unroll
    for (int ti = 0; ti < 2; ++ti) {
        int tile = u + ti * 4;
        int tc   = tile > 5 ? 5 : tile;
        int grow = tc * 16 + lr;
        int p    = grow > 80 ? 80 : grow;
        int oh   = (p * 57) >> 9;
        int ow   = p - oh * 9;
        rowbase[ti] = oh * 432 + ow * 16;          // bytes
        pbase[ti]   = tc * 16 + g * 4;             // C rows p = pbase + r
    }

    // staging identity: 192 threads = (ci,row) x half
    const bool stg  = t < 192;
    const int  r_   = t >> 1;                      // 0..95
    const int  half = t & 1;
    const int  sci  = r_ >> 5;
    const int  srow = r_ & 31;
    const int  goff = sci * 1024 + srow * 32 + (half ? 12 : 0);
    f16* wptr = WINH + sci * 2304 + srow * 72;

    // prologue: load + stage sample 0; zero YS tails (halves [324,360) per sample)
    float4 ldv[5];
    if (stg) {
        const float* gp = x + base_s * 3072 + goff;
#pragma unroll
        for (int i = 0; i < 5; ++i) ldv[i] = *(const float4*)(gp + 4 * i);
    }
#pragma unroll
    for (int i = 0; i < 3; ++i) {
        int idx = i * 256 + t;
        if (idx < NS * 18) {
            int si = idx / 18, d = idx - si * 18;
            *(unsigned*)(YS + si * 360 + 324 + d * 2) = 0u;
        }
    }
    if (stg) write_half(wptr, ldv, half);
    __syncthreads();

    for (int s = 0; s < NS; ++s) {
        if (s < NS - 1 && stg) {
            const float* gp = x + (base_s + s + 1) * 3072 + goff;
#pragma unroll
            for (int i = 0; i < 5; ++i) ldv[i] = *(const float4*)(gp + 4 * i);
        }
        f16* ysp = YS + s * 360;
        __builtin_amdgcn_s_setprio(1);
#pragma unroll
        for (int ti = 0; ti < 2; ++ti) {
            if (ti < ntiles) {
                const unsigned char* pA = lds + rowbase[ti];
                f32x4 acc = {0.f, 0.f, 0.f, 0.f};
#pragma unroll
                for (int st = 0; st < 6; ++st) {
                    f16x8 af = *(const f16x8*)(pA + seg2off[st]);
                    acc = __builtin_amdgcn_mfma_f32_16x16x32_f16(af, wcf[st], acc, 0, 0, 0);
                }
                if (lr < 4) {
#pragma unroll
                    for (int r = 0; r < 4; ++r) {
                        int p = pbase[ti] + r;
                        if (p < 81) {
                            float y = acc[r];
                            ysp[lr * 81 + p] = (f16)(y * y);
                        }
                    }
                }
            }
        }
        __builtin_amdgcn_s_setprio(0);
        __syncthreads();                       // WIN reads done, YS visible
        if (s < NS - 1) {
            if (stg) write_half(wptr, ldv, half);
            __syncthreads();                   // WIN ready for next sample
        }
    }

    // ---- fc1: M=32 (two 16-row tiles share one weight load/split), N=64, K=352 ----
    {
        f32x4 a0 = {0.f, 0.f, 0.f, 0.f};
        f32x4 a1 = {0.f, 0.f, 0.f, 0.f};
        const int n = w * 16 + lr;
        const float* w1r = fc1w + n * 324;
        __builtin_amdgcn_s_setprio(1);
#pragma unroll
        for (int st = 0; st < 10; ++st) {
            f16x8 av0 = *(const f16x8*)(YS +        lr  * 360 + st * 32 + g * 8);
            f16x8 av1 = *(const f16x8*)(YS + (16 + lr) * 360 + st * 32 + g * 8);
            float4 v0 = *(const float4*)(w1r + st * 32 + g * 8);
            float4 v1 = *(const float4*)(w1r + st * 32 + g * 8 + 4);
            float vv[8] = {v0.x, v0.y, v0.z, v0.w, v1.x, v1.y, v1.z, v1.w};
            f16x8 bh, bl;
#pragma unroll
            for (int j = 0; j < 8; ++j) {
                f16 hi = (f16)vv[j];
                bh[j] = hi;
                bl[j] = (f16)(vv[j] - (float)hi);
            }
            a0 = __builtin_amdgcn_mfma_f32_16x16x32_f16(av0, bh, a0, 0, 0, 0);
            a0 = __builtin_amdgcn_mfma_f32_16x16x32_f16(av0, bl, a0, 0, 0, 0);
            a1 = __builtin_amdgcn_mfma_f32_16x16x32_f16(av1, bh, a1, 0, 0, 0);
            a1 = __builtin_amdgcn_mfma_f32_16x16x32_f16(av1, bl, a1, 0, 0, 0);
        }
        {   // st = 10: k = 320..351, only 320..323 carry data (g==0, j<4)
            f16x8 av0 = *(const f16x8*)(YS +        lr  * 360 + 320 + g * 8);
            f16x8 av1 = *(const f16x8*)(YS + (16 + lr) * 360 + 320 + g * 8);
            f16x8 bh = {0,0,0,0,0,0,0,0}, bl = {0,0,0,0,0,0,0,0};
            if (g == 0) {
                float4 v0 = *(const float4*)(w1r + 320);
                float vv[4] = {v0.x, v0.y, v0.z, v0.w};
#pragma unroll
                for (int j = 0; j < 4; ++j) {
                    f16 hi = (f16)vv[j];
                    bh[j] = hi;
                    bl[j] = (f16)(vv[j] - (float)hi);
                }
            }
            a0 = __builtin_amdgcn_mfma_f32_16x16x32_f16(av0, bh, a0, 0, 0, 0);
            a0 = __builtin_amdgcn_mfma_f32_16x16x32_f16(av0, bl, a0, 0, 0, 0);
            a1 = __builtin_amdgcn_mfma_f32_16x16x32_f16(av1, bh, a1, 0, 0, 0);
            a1 = __builtin_amdgcn_mfma_f32_16x16x32_f16(av1, bl, a1, 0, 0, 0);
        }
        __builtin_amdgcn_s_setprio(0);
        float bias = fc1b[n];
#pragma unroll
        for (int r = 0; r < 4; ++r) {
            int s0 = g * 4 + r;                // samples 0..15
            float h0 = a0[r] + bias;
            HSQ[s0 * 65 + n] = h0 * h0;
            float h1 = a1[r] + bias;           // samples 16..31
            HSQ[(s0 + 16) * 65 + n] = h1 * h1;
        }
    }
    __syncthreads();

    // ---------------- fc2: NS*10 = 320 outputs ----------------
#pragma unroll
    for (int b = 0; b < 2; ++b) {
        int idx = b * 256 + t;
        if (idx < NS * 10) {
            int sj = idx / 10, j = idx - sj * 10;
            float a = fc2b[j];
            const float* wr = fc2w + j * 64;
            const float* hv = &HSQ[sj * 65];
#pragma unroll
            for (int i = 0; i < 64; ++i) a += wr[i] * hv[i];
            out[(base_s + sj) * 10 + j] = a;
        }
    }
}

extern "C" void kernel_launch(void* const* d_in, const int* in_sizes, int n_in,
                              void* d_out, int out_size, void* d_ws, size_t ws_size,
                              hipStream_t stream) {
    const float* x    = (const float*)d_in[0];
    const float* cw   = (const float*)d_in[1];
    const float* fc1w = (const float*)d_in[2];
    const float* fc1b = (const float*)d_in[3];
    const float* fc2w = (const float*)d_in[4];
    const float* fc2b = (const float*)d_in[5];
    float* out = (float*)d_out;

    const int B = in_sizes[0] / 3072;      // 16384
    hipLaunchKernelGGL(convnet_mfma, dim3(B / NS), dim3(256), 0, stream,
                       x, cw, fc1w, fc1b, fc2w, fc2b, out);
}